// Round 2
// baseline (119.579 us; speedup 1.0000x reference)
//
#include <hip/hip_runtime.h>

// Problem constants
#define B_   16
#define N_   128
#define H_   32
#define D_   5
#define NEF_ 3
#define NE1  1537   // NUM_EDGES + 1
#define NP1  129    // N + 1

// ---------------------------------------------------------------------------
// Kernel 1: fused[d][idx][k] = sum_h edge_encoder_w[idx][h] * Wdis[d][h][k]
// Wdis[d] = edge_dis_w.reshape(-1,32,32)[d]  (row-major [h][k])
// Grid: 5 * ceil(1537/8) = 965 blocks of 256 threads; 8 idx rows per block.
// ---------------------------------------------------------------------------
__global__ __launch_bounds__(256) void fused_tab_kernel(
    const float* __restrict__ edge_encoder_w,   // (1537, 32)
    const float* __restrict__ edge_dis_w,       // (131072,)
    float* __restrict__ fused)                  // (5, 1537, 32)
{
    __shared__ float wd[32 * 32];
    const int tid = threadIdx.x;
    const int bx  = blockIdx.x;
    const int d     = bx / 193;
    const int chunk = bx % 193;

    // Load Wdis[d] (32x32 fp32 = 4 KB) into LDS
    const float* wsrc = edge_dis_w + d * 1024;
    for (int k = tid; k < 1024; k += 256) wd[k] = wsrc[k];
    __syncthreads();

    const int g    = tid >> 5;
    const int lane = tid & 31;       // lane = output index k
    const int idx  = chunk * 8 + g;
    if (idx >= NE1) return;

    float w = edge_encoder_w[idx * 32 + lane];  // lane's slice of the input row
    float acc = 0.f;
    #pragma unroll
    for (int hh = 0; hh < 32; ++hh) {
        acc += __shfl(w, hh, 32) * wd[hh * 32 + lane];
    }
    fused[(d * NE1 + idx) * 32 + lane] = acc;
}

// ---------------------------------------------------------------------------
// Kernel 2: inner cells (i,j in [1,128]).
// One 32-lane group per (b, i, j) cell; lane = h. Block = 256 threads handles
// one (b, i, jt) tile of 32 consecutive j. Results staged in LDS for
// coalesced j-major stores.
// Grid: B * 128 * 4 = 8192 blocks.
// ---------------------------------------------------------------------------
__global__ __launch_bounds__(256) void main_kernel(
    const float* __restrict__ attn_bias,    // (16, 129, 129)
    const int*   __restrict__ spatial_pos,  // (16, 128, 128)
    const int*   __restrict__ edge_input,   // (16, 128, 128, 5, 3)
    const float* __restrict__ structural_w, // (512, 32)
    const float* __restrict__ fused,        // (5, 1537, 32)
    float* __restrict__ out)                // (16, 32, 129, 129)
{
    __shared__ float tile[32][33];          // [h][j_local], +1 pad: conflict-free

    const int bx  = blockIdx.x;
    const int jt  = bx & 3;                 // j tile (32 j's each)
    const int i   = (bx >> 2) & 127;
    const int b   = bx >> 9;
    const int tid  = threadIdx.x;
    const int g    = tid >> 5;
    const int lane = tid & 31;              // = h in phase 1, = j offset in phase 2

    #pragma unroll
    for (int jj = 0; jj < 4; ++jj) {
        const int jl = g * 4 + jj;          // 0..31
        const int j  = jt * 32 + jl;        // 0..127
        const int cell = (b * N_ + i) * N_ + j;

        const int* eip = edge_input + cell * (D_ * NEF_);
        int my_idx = (lane < 15) ? eip[lane] : 0;
        const int sp0 = spatial_pos[cell];

        float acc = 0.f;
        #pragma unroll
        for (int t = 0; t < 15; ++t) {
            const int id = __shfl(my_idx, t, 32);
            const int d  = t / 3;           // compile-time per unrolled t
            acc += fused[(d * NE1 + id) * 32 + lane];
        }

        // sp = clip(transform, 1..5)
        int s = sp0;
        if (s == 0) s = 1;
        if (s > 1)  s -= 1;
        if (s > D_) s = D_;

        float val = acc / (3.0f * (float)s) + structural_w[sp0 * 32 + lane];
        tile[lane][jl] = val;
    }
    __syncthreads();

    // Phase 2: coalesced stores. lane = j offset within tile, rows are h.
    const int j = jt * 32 + lane + 1;                       // output j in [1,128]
    const float ab2 = 2.0f * attn_bias[(b * NP1 + (i + 1)) * NP1 + j];
    #pragma unroll
    for (int rr = 0; rr < 4; ++rr) {
        const int h = g + rr * 8;
        out[((b * H_ + h) * NP1 + (i + 1)) * NP1 + j] = ab2 + tile[h][lane];
    }
}

// ---------------------------------------------------------------------------
// Kernel 3: borders. Row i=0 (all j, incl. j=0) and column j=0 (i>=1):
//   out = 2*attn_bias + virt_w[h]
// Grid: B*H = 512 blocks of 256 threads.
// ---------------------------------------------------------------------------
__global__ __launch_bounds__(256) void border_kernel(
    const float* __restrict__ attn_bias,    // (16, 129, 129)
    const float* __restrict__ virt_w,       // (1, 32)
    float* __restrict__ out)                // (16, 32, 129, 129)
{
    const int bh = blockIdx.x;              // 0..511
    const int b = bh >> 5;
    const int h = bh & 31;
    const float t = virt_w[h];

    float*       ob = out + (b * H_ + h) * NP1 * NP1;
    const float* ab = attn_bias + b * NP1 * NP1;

    for (int idx = threadIdx.x; idx < NP1 + N_; idx += 256) {
        if (idx < NP1) {
            // row i = 0, j = idx (0..128)
            ob[idx] = 2.0f * ab[idx] + t;
        } else {
            // column j = 0, i = idx - 128 (1..128)
            const int i = idx - 128;
            ob[i * NP1] = 2.0f * ab[i * NP1] + t;
        }
    }
}

// ---------------------------------------------------------------------------
extern "C" void kernel_launch(void* const* d_in, const int* in_sizes, int n_in,
                              void* d_out, int out_size, void* d_ws, size_t ws_size,
                              hipStream_t stream) {
    // setup_inputs() order:
    // 0: x (unused)  1: attn_bias  2: spatial_pos  3: edge_input
    // 4: edge_encoder_w  5: structural_w  6: edge_dis_w  7: virt_w
    const float* attn_bias      = (const float*)d_in[1];
    const int*   spatial_pos    = (const int*)  d_in[2];
    const int*   edge_input     = (const int*)  d_in[3];
    const float* edge_encoder_w = (const float*)d_in[4];
    const float* structural_w   = (const float*)d_in[5];
    const float* edge_dis_w     = (const float*)d_in[6];
    const float* virt_w         = (const float*)d_in[7];
    float* out   = (float*)d_out;
    float* fused = (float*)d_ws;   // needs 5*1537*32*4 = 983,680 B

    hipLaunchKernelGGL(fused_tab_kernel, dim3(5 * 193), dim3(256), 0, stream,
                       edge_encoder_w, edge_dis_w, fused);
    hipLaunchKernelGGL(main_kernel, dim3(B_ * N_ * 4), dim3(256), 0, stream,
                       attn_bias, spatial_pos, edge_input, structural_w, fused, out);
    hipLaunchKernelGGL(border_kernel, dim3(B_ * H_), dim3(256), 0, stream,
                       attn_bias, virt_w, out);
}